// Round 9
// baseline (51.325 us; speedup 1.0000x reference)
//
#include <hip/hip_runtime.h>

// ---------------------------------------------------------------------------
// Depthwise 1-D full correlation, per (batch, filter):
//   out[t] = sum_s y[s] * w[2047 + s - t],   t, s in [0, 4096)
// Slab per (b,f) (ushort units), IMAGE is gload_lds'd linearly into LDS:
//   [0,8448)       y-region PRE-SWIZZLED (y[s] at swz-gran of 2048+s, 0-pads)
//   [8448,12592)   WA image: WA[16+i]=w[i], 0-pads
//   [12592,16736)  WB image: WB[15+i]=w[i], 0-pads  (+1 shift prebuilt by K0)
//   [16736,18432)  pad (DMA'd, never read)
//   [18432,26624)  out f32[4096]
// K0: transpose/convert X -> slab images (incl. swizzle + WB shift)
// K1: 512 blocks x 2 (b,f) pairs, double-buffered LDS; async global_load_lds
//     staging overlapped with compute via counted vmcnt + raw s_barrier;
//     R5-verified 16h x 2p MFMA core; 3-phase swizzled f32x4 reduction.
// K2: 32x32 transpose out-regions -> out[b][t][f]; one writer per 128-B line.
// All kernels: b = bid&31 so bid%8==b%8 -> slab pipeline XCD-local.
// ---------------------------------------------------------------------------

#define T_LEN 4096
#define F_CH  32

#define IMG_US  18432             // 2304 granules staged per pair
#define WA_OFF  8448
#define WB_OFF  12592
#define O_OFF   18432
#define SLAB_US 26624             // 53248 B/slab; 1024 slabs = 54.5 MB

using short8 = __attribute__((ext_vector_type(8))) short;
using f32x4  = __attribute__((ext_vector_type(4))) float;
using uint4v = __attribute__((ext_vector_type(4))) unsigned int;

__device__ __forceinline__ unsigned short bf16b(float x) {
    unsigned int u = __float_as_uint(x);
    u += 0x7FFFu + ((u >> 16) & 1u);      // RNE
    return (unsigned short)(u >> 16);
}

// y swizzle (granule XOR, bijective per 8-set); RSWZ: reduction swizzle
#define GSWZ(g)  ((g) ^ (((g) >> 3) & 7))
#define YADDR(e) ((GSWZ((e) >> 3)) << 3)
#define RSWZ(j)  ((j) ^ ((((j) >> 4) & 7) << 2))

__device__ __forceinline__ void gload16(const unsigned short* g, unsigned short* l) {
    __builtin_amdgcn_global_load_lds(
        (const __attribute__((address_space(1))) void*)g,
        (__attribute__((address_space(3))) void*)l, 16, 0, 0);
}

// ---------------------------------------------------------------------------
__global__ __launch_bounds__(256)
void k0_stage(const float* __restrict__ X, unsigned short* __restrict__ ws) {
    __shared__ unsigned short tile[64 * 130];
    const int tid = threadIdx.x;
    const int b    = blockIdx.x & 31;            // bid%8 == b%8 (XCD-local)
    const int tpos = blockIdx.x >> 5;            // 0..31
    const int s0   = tpos << 7;                  // 128-row stripe

    unsigned short* wsb = ws + (size_t)b * 32 * SLAB_US;
    const f32x4 zf = (f32x4)0.0f;

    // ---- y-region zero pads (swizzled granule positions) ----
    {   // lpad granules [0,256): 8 per stripe per f
        int f = tid >> 3, kk = tid & 7;
        int g = tpos * 8 + kk;
        *(f32x4*)(wsb + (size_t)f * SLAB_US + (GSWZ(g) << 3)) = zf;
    }
    for (int i = tid; i < 288; i += 256) {       // rpad granules [768,1056)
        int f = i / 9, kk = i - 9 * f;
        int g = 768 + tpos * 9 + kk;
        *(f32x4*)(wsb + (size_t)f * SLAB_US + (GSWZ(g) << 3)) = zf;
    }
    // ---- WA/WB pad zeros (tpos==0 only): 47 dwords per f ----
    if (tpos == 0) {
        for (int i = tid; i < 32 * 47; i += 256) {
            int f = i / 47, z = i - 47 * f;
            int us;
            if (z < 8)       us = WA_OFF + 2 * z;                 // WA [0,16)
            else if (z < 24) us = WA_OFF + 4112 + 2 * (z - 8);    // WA [4112,4144)
            else if (z < 31) us = WB_OFF + 2 * (z - 24);          // WB [0,14)
            else             us = WB_OFF + 4112 + 2 * (z - 31);   // WB [4112,4144)
            *(unsigned int*)(wsb + (size_t)f * SLAB_US + us) = 0u;
        }
    }

    // ---- transpose 128 x 64 tile ----
    const float* xb = X + ((size_t)b * T_LEN + s0) * 64;
#pragma unroll
    for (int i = 0; i < 8; ++i) {
        int d4 = 4 * (tid + 256 * i);
        int row = d4 >> 6, c0 = d4 & 63;
        f32x4 xv = *(const f32x4*)(xb + (size_t)row * 64 + c0);
#pragma unroll
        for (int k = 0; k < 4; ++k)
            tile[(c0 + k) * 130 + row] = bf16b(xv[k]);
    }
    __syncthreads();

    // ---- y (pre-swizzled) & WA writes (dword, coalesced per wave) ----
#pragma unroll
    for (int i = 0; i < 16; ++i) {
        int dw = tid + 256 * i;                  // 0..4095
        int c = dw >> 6, j0 = (dw & 63) * 2;
        unsigned int two = *(const unsigned int*)(tile + c * 130 + j0);
        if (c < 32) {
            int e = 2048 + s0 + j0;              // linear y ushort index
            int us = (GSWZ(e >> 3) << 3) | (j0 & 7);
            *(unsigned int*)(wsb + (size_t)c * SLAB_US + us) = two;
        } else {
            *(unsigned int*)(wsb + (size_t)(c - 32) * SLAB_US
                             + (WA_OFF + 16 + s0 + j0)) = two;
        }
    }

    // ---- WB image: dword (w[s0+2k-1], w[s0+2k]) at WB_OFF+14+s0+2k ----
#pragma unroll
    for (int i = 0; i < 8; ++i) {
        int dw = tid + 256 * i;                  // 0..2047
        int c = dw >> 6, k = dw & 63;
        unsigned short lo;
        if (k == 0)
            lo = (s0 > 0) ? bf16b(X[((size_t)b * T_LEN + s0 - 1) * 64 + 32 + c])
                          : (unsigned short)0;
        else
            lo = tile[(c + 32) * 130 + 2 * k - 1];
        unsigned short hi = tile[(c + 32) * 130 + 2 * k];
        unsigned int two = (unsigned int)lo | ((unsigned int)hi << 16);
        *(unsigned int*)(wsb + (size_t)c * SLAB_US
                         + (WB_OFF + 14 + s0 + 2 * k)) = two;
        if (k == 63 && s0 == T_LEN - 128) {      // tail: (w[4095], 0) at us 4110
            unsigned int tl = (unsigned int)tile[(c + 32) * 130 + 127];
            *(unsigned int*)(wsb + (size_t)c * SLAB_US + (WB_OFF + 4110)) = tl;
        }
    }
}

// ---------------------------------------------------------------------------
// R5-verified compute core + exchange + out-store for one (b,f) pair.
__device__ __forceinline__ void do_pair(unsigned short* lb,
                                        unsigned short* slab, int tid) {
    const int lane = tid & 63;
    const int wv   = tid >> 6;
    const int nn   = lane & 15;
    const int q    = lane >> 4;
    const int ko   = q << 3;

    f32x4 acc[16];
#pragma unroll
    for (int h = 0; h < 16; ++h) acc[h] = (f32x4)0.0f;
    short8 cache[16];

    const int tiOdd = nn & 1;
    const unsigned short* wbase = tiOdd ? (lb + WA_OFF) : (lb + WB_OFF);
    const int aoff0 = (tiOdd ? 15 : 14) + ko - nn;           // even, >= 0
    const unsigned short* ybase = lb;
    const int yoff0 = 16 * nn + ko;

    for (int pp = 0; pp < 2; ++pp) {
        const int p = wv * 2 + pp;                           // pass 0..7
        const int yoff = yoff0 + 32 * p;
        const unsigned int* abase =
            (const unsigned int*)(wbase + (aoff0 + 32 * p));

#pragma unroll
        for (int s = 0; s < 16; ++s)
            cache[s] = *(const short8*)(ybase + YADDR(yoff + 256 * s));

#pragma unroll
        for (int M = 0; M < 16; ++M) {
            unsigned int a0 = abase[128 * M + 0];
            unsigned int a1 = abase[128 * M + 1];
            unsigned int a2 = abase[128 * M + 2];
            unsigned int a3 = abase[128 * M + 3];
            uint4v av = {a0, a1, a2, a3};
            short8 af = __builtin_bit_cast(short8, av);
            __builtin_amdgcn_s_setprio(1);
#pragma unroll
            for (int h = 0; h < 16; ++h)
                acc[h] = __builtin_amdgcn_mfma_f32_16x16x32_bf16(
                    af, cache[(h + M) & 15], acc[h], 0, 0, 0);
            __builtin_amdgcn_s_setprio(0);
            cache[M] = *(const short8*)(ybase + YADDR(yoff + 256 * (M + 16)));
        }

        if (p == 0) {                                        // extra M=16
            unsigned int a0 = abase[2048];
            unsigned int a1 = abase[2049];
            unsigned int a2 = abase[2050];
            unsigned int a3 = abase[2051];
            uint4v av = {a0, a1, a2, a3};
            short8 af = __builtin_bit_cast(short8, av);
            __builtin_amdgcn_s_setprio(1);
#pragma unroll
            for (int h = 0; h < 16; ++h)
                acc[h] = __builtin_amdgcn_mfma_f32_16x16x32_bf16(
                    af, cache[h], acc[h], 0, 0, 0);
            __builtin_amdgcn_s_setprio(0);
        }
    }

    // ---- 3-phase swizzled reduction (red overlays this pair's buffer) ----
    __syncthreads();                  // also drains vmcnt -> other buf ready
    float* red = (float*)lb;
    const int jb = RSWZ(16 * nn + 4 * q);

    if (wv >= 2) {
        float* dst = red + (wv - 2) * 4096;
#pragma unroll
        for (int h = 0; h < 16; ++h)
            *(f32x4*)(dst + 256 * h + jb) = acc[h];
    }
    __syncthreads();
    if (wv < 2) {
        const float* src = red + wv * 4096;
#pragma unroll
        for (int h = 0; h < 16; ++h)
            acc[h] += *(const f32x4*)(src + 256 * h + jb);
    }
    __syncthreads();
    if (wv < 2) {
        float* dst = red + wv * 4096;
#pragma unroll
        for (int h = 0; h < 16; ++h)
            *(f32x4*)(dst + 256 * h + jb) = acc[h];
    }
    __syncthreads();

    float* slabf = (float*)(slab + O_OFF);
#pragma unroll
    for (int j = 0; j < 4; ++j) {
        int t = 4 * tid + 1024 * j;
        int ph = (t & ~255) + RSWZ(t & 255);
        f32x4 v0 = *(const f32x4*)(red + ph);
        f32x4 v1 = *(const f32x4*)(red + 4096 + ph);
        *(f32x4*)(slabf + t) = v0 + v1;
    }
}

__global__ __launch_bounds__(256, 2)
void corr1d_mfma_kernel(unsigned short* __restrict__ ws) {
    __shared__ __align__(16) unsigned short lds[2 * IMG_US];   // 73728 B
    const int tid = threadIdx.x;
    const int bid = blockIdx.x;                  // 512 blocks, 2 per CU
    const int b  = bid & 31;                     // bid%8 == b%8 (XCD-local)
    const int fp = bid >> 5;                     // 0..15
    unsigned short* slab0 = ws + (size_t)(b * 32 + 2 * fp) * SLAB_US;
    unsigned short* slab1 = slab0 + SLAB_US;

    // ---- async stage: buf0 then buf1 (9 x 16B per thread each) ----
#pragma unroll
    for (int r = 0; r < 9; ++r) {
        int g8 = (tid + 256 * r) * 8;
        gload16(slab0 + g8, lds + g8);
    }
#pragma unroll
    for (int r = 0; r < 9; ++r) {
        int g8 = (tid + 256 * r) * 8;
        gload16(slab1 + g8, lds + IMG_US + g8);
    }
    asm volatile("s_waitcnt vmcnt(9)" ::: "memory");   // buf0 done, buf1 in flight
    __builtin_amdgcn_s_barrier();
    __builtin_amdgcn_sched_barrier(0);

    do_pair(lds, slab0, tid);                    // buf1 DMA hides under this
    do_pair(lds + IMG_US, slab1, tid);           // vmcnt drained by syncthreads
}

// ---------------------------------------------------------------------------
__global__ __launch_bounds__(256)
void k2_out(const unsigned short* __restrict__ ws, float* __restrict__ out) {
    __shared__ float tile[32][33];
    const int blk = blockIdx.x;
    const int b  = blk & 31;                     // bid%8 == b%8 (XCD-local)
    const int t0 = (blk >> 5) << 5;
    const int a  = threadIdx.x >> 5;
    const int j  = threadIdx.x & 31;

#pragma unroll
    for (int ff = a; ff < 32; ff += 8)
        tile[ff][j] =
            ((const float*)(ws + (size_t)(b * 32 + ff) * SLAB_US + O_OFF))[t0 + j];
    __syncthreads();
#pragma unroll
    for (int jj = a; jj < 32; jj += 8)
        out[b * (T_LEN * F_CH) + (t0 + jj) * F_CH + j] = tile[j][jj];
}

// ---------------------------------------------------------------------------
extern "C" void kernel_launch(void* const* d_in, const int* in_sizes, int n_in,
                              void* d_out, int out_size, void* d_ws, size_t ws_size,
                              hipStream_t stream) {
    const float* X = (const float*)d_in[0];
    float* out = (float*)d_out;
    (void)in_sizes; (void)n_in; (void)out_size; (void)ws_size;
    unsigned short* ws = (unsigned short*)d_ws;

    k0_stage<<<dim3(1024), dim3(256), 0, stream>>>(X, ws);
    corr1d_mfma_kernel<<<dim3(512), dim3(256), 0, stream>>>(ws);
    k2_out<<<dim3(4096), dim3(256), 0, stream>>>(ws, out);
}

// Round 10
// 47.136 us; speedup vs baseline: 1.0889x; 1.0889x over previous
//
#include <hip/hip_runtime.h>

// ---------------------------------------------------------------------------
// Depthwise 1-D full correlation, per (batch, filter):
//   out[t] = sum_s y[s] * w[2047 + s - t],   t, s in [0, 4096)
// Slab per (b,f) (ushort units):
//   [0,8448)       y-image, PRE-SWIZZLED (y[s] at swz-granule of 2048+s,
//                  zero pads at swz positions) -> DMA-ready for K1
//   [8448,12544)   w[4096]
//   [12544,20736)  out f32[4096]
// K0: transpose/convert X -> slab images (pre-swizzled y + pads, w)
// K1: one block per (b,f); y staged via global_load_lds (width 16, linear);
//     WA/WB (+1 shift) built from registers; R5-verified 16h x 2p MFMA core;
//     swizzled f32x4 3-phase reduction; f32 result to own slab.
// K2: 32x32 transpose out-regions -> out[b][t][f]; one writer per 128-B line.
// All kernels: b = bid&31 so bid%8==b%8 -> slab pipeline XCD-local (perf only).
// ---------------------------------------------------------------------------

#define T_LEN 4096
#define F_CH  32
#define SLAB_US 20736
#define W_OFF 8448
#define O_OFF 12544

// K1 LDS layout (ushort units) — identical image to R5's post-stage LDS
#define WAo    8448               // WA[16+i] = w[i]
#define WBo    12592              // WB[15+i] = w[i]  (built during staging)
#define LDS_US 16736              // 33472 B

using short8 = __attribute__((ext_vector_type(8))) short;
using f32x4  = __attribute__((ext_vector_type(4))) float;
using uint4v = __attribute__((ext_vector_type(4))) unsigned int;

__device__ __forceinline__ unsigned short bf16b(float x) {
    unsigned int u = __float_as_uint(x);
    u += 0x7FFFu + ((u >> 16) & 1u);      // RNE
    return (unsigned short)(u >> 16);
}

// y swizzle: granule g -> g ^ ((g>>3)&7)  (bijective per 8-block)
#define GSWZ(g)  ((g) ^ (((g) >> 3) & 7))
#define YADDR(e) ((GSWZ((e) >> 3)) << 3)
// reduction swizzle within a 256-dword h-block (R5-verified)
#define RSWZ(j)  ((j) ^ ((((j) >> 4) & 7) << 2))

__device__ __forceinline__ void gload16(const unsigned short* g, unsigned short* l) {
    __builtin_amdgcn_global_load_lds(
        (const __attribute__((address_space(1))) void*)g,
        (__attribute__((address_space(3))) void*)l, 16, 0, 0);
}

// ---------------------------------------------------------------------------
__global__ __launch_bounds__(256)
void k0_stage(const float* __restrict__ X, unsigned short* __restrict__ ws) {
    __shared__ unsigned short tile[64 * 130];
    const int tid = threadIdx.x;
    const int b    = blockIdx.x & 31;            // bid%8 == b%8 (XCD-local)
    const int tpos = blockIdx.x >> 5;            // 0..31
    const int s0   = tpos << 7;                  // 128-row stripe

    unsigned short* wsb = ws + (size_t)b * 32 * SLAB_US;
    const f32x4 zf = (f32x4)0.0f;

    // ---- y-image zero pads (pre-swizzled granule positions) ----
    {   // lpad granules [0,256): 8 per stripe per f
        int f = tid >> 3, kk = tid & 7;
        int g = tpos * 8 + kk;
        *(f32x4*)(wsb + (size_t)f * SLAB_US + (GSWZ(g) << 3)) = zf;
    }
    for (int i = tid; i < 288; i += 256) {       // rpad granules [768,1056)
        int f = i / 9, kk = i - 9 * f;
        int g = 768 + tpos * 9 + kk;
        *(f32x4*)(wsb + (size_t)f * SLAB_US + (GSWZ(g) << 3)) = zf;
    }

    // ---- transpose 128 x 64 tile ----
    const float* xb = X + ((size_t)b * T_LEN + s0) * 64;
#pragma unroll
    for (int i = 0; i < 8; ++i) {
        int d4 = 4 * (tid + 256 * i);
        int row = d4 >> 6, c0 = d4 & 63;
        f32x4 xv = *(const f32x4*)(xb + (size_t)row * 64 + c0);
#pragma unroll
        for (int k = 0; k < 4; ++k)
            tile[(c0 + k) * 130 + row] = bf16b(xv[k]);
    }
    __syncthreads();

    // ---- write y (pre-swizzled) & w slabs (dword stores, coalesced) ----
#pragma unroll
    for (int i = 0; i < 16; ++i) {
        int dw = tid + 256 * i;                  // 0..4095
        int c = dw >> 6, j0 = (dw & 63) * 2;
        unsigned int two = *(const unsigned int*)(tile + c * 130 + j0);
        if (c < 32) {
            int e = 2048 + s0 + j0;              // linear y ushort index
            int us = (GSWZ(e >> 3) << 3) | (j0 & 7);
            *(unsigned int*)(wsb + (size_t)c * SLAB_US + us) = two;
        } else {
            *(unsigned int*)(wsb + (size_t)(c - 32) * SLAB_US
                             + (W_OFF + s0 + j0)) = two;
        }
    }
}

// ---------------------------------------------------------------------------
__global__ __launch_bounds__(256, 2)
void corr1d_mfma_kernel(unsigned short* __restrict__ ws) {
    __shared__ __align__(16) unsigned short lds[LDS_US];
    const int tid = threadIdx.x;
    const int b = blockIdx.x & 31;               // bid%8 == b%8 (XCD-local)
    const int f = blockIdx.x >> 5;
    unsigned short* slab = ws + (size_t)(b * 32 + f) * SLAB_US;

    // ---- y DMA: 1056 granules, linear both sides (image pre-swizzled) ----
#pragma unroll
    for (int r = 0; r < 4; ++r) {
        int g8 = (tid + 256 * r) * 8;
        gload16(slab + g8, lds + g8);
    }
    if (tid < 32) {
        int g8 = (1024 + tid) * 8;
        gload16(slab + g8, lds + g8);
    }

    // ---- zero W pad regions ----
    f32x4 z4 = (f32x4)0.0f;
    if (tid < 2)       *(f32x4*)(lds + WAo + 8 * tid) = z4;              // WA [0,16)
    else if (tid < 6)  *(f32x4*)(lds + WAo + 4112 + 8 * (tid - 2)) = z4; // WA [4112,4144)
    else if (tid == 6) {
        *(f32x4*)(lds + WBo) = z4;                                       // WB [0,8)
        for (int i = 8; i < 14; ++i) lds[WBo + i] = 0;                   // WB [8,14)
    } else if (tid >= 8 && tid < 12)
        *(f32x4*)(lds + WBo + 4112 + 8 * (tid - 8)) = z4;                // WB [4112,4144)

    // ---- stage WA, build WB (+1 shift) from registers ----
    const uint4v* sv = (const uint4v*)(slab + W_OFF);
    unsigned int* wb32 = (unsigned int*)(lds + WBo);
#pragma unroll
    for (int r = 0; r < 2; ++r) {
        int c = tid + 256 * r;                   // 0..511
        uint4v vw = sv[c];                       // w[8c .. 8c+7]
        *(uint4v*)(lds + WAo + 16 + 8 * c) = vw;
        unsigned int wm1 = (c == 0) ? 0u
                         : (unsigned int)slab[W_OFF + 8 * c - 1];
        unsigned int v0 = vw[0], v1 = vw[1], v2 = vw[2], v3 = vw[3];
        wb32[7 + 4 * c + 0] = (wm1 & 0xFFFFu) | (v0 << 16);
        wb32[7 + 4 * c + 1] = (v0 >> 16) | (v1 << 16);
        wb32[7 + 4 * c + 2] = (v1 >> 16) | (v2 << 16);
        wb32[7 + 4 * c + 3] = (v2 >> 16) | (v3 << 16);
        if (c == 511) wb32[2055] = (v3 >> 16);   // (w[4095], 0)
    }
    __syncthreads();                             // drains DMA (vmcnt) + ds

    // ---- compute (R5-verified core; no setprio) ----
    const int lane = tid & 63;
    const int wv   = tid >> 6;
    const int nn   = lane & 15;
    const int q    = lane >> 4;
    const int ko   = q << 3;

    f32x4 acc[16];
#pragma unroll
    for (int h = 0; h < 16; ++h) acc[h] = (f32x4)0.0f;

    short8 cache[16];

    const int tiOdd = nn & 1;
    const unsigned short* wbase = tiOdd ? &lds[WAo] : &lds[WBo];
    const int aoff0 = (tiOdd ? 15 : 14) + ko - nn;           // even, >= 0
    const unsigned short* ybase = &lds[0];
    const int yoff0 = 16 * nn + ko;

    for (int pp = 0; pp < 2; ++pp) {
        const int p = wv * 2 + pp;                           // pass 0..7
        const int yoff = yoff0 + 32 * p;
        const unsigned int* abase =
            (const unsigned int*)(wbase + (aoff0 + 32 * p));

#pragma unroll
        for (int s = 0; s < 16; ++s)
            cache[s] = *(const short8*)(ybase + YADDR(yoff + 256 * s));

#pragma unroll
        for (int M = 0; M < 16; ++M) {
            unsigned int a0 = abase[128 * M + 0];
            unsigned int a1 = abase[128 * M + 1];
            unsigned int a2 = abase[128 * M + 2];
            unsigned int a3 = abase[128 * M + 3];
            uint4v av = {a0, a1, a2, a3};
            short8 af = __builtin_bit_cast(short8, av);
#pragma unroll
            for (int h = 0; h < 16; ++h)
                acc[h] = __builtin_amdgcn_mfma_f32_16x16x32_bf16(
                    af, cache[(h + M) & 15], acc[h], 0, 0, 0);
            cache[M] = *(const short8*)(ybase + YADDR(yoff + 256 * (M + 16)));
        }

        if (p == 0) {                                        // extra M=16
            unsigned int a0 = abase[2048];
            unsigned int a1 = abase[2049];
            unsigned int a2 = abase[2050];
            unsigned int a3 = abase[2051];
            uint4v av = {a0, a1, a2, a3};
            short8 af = __builtin_bit_cast(short8, av);
#pragma unroll
            for (int h = 0; h < 16; ++h)
                acc[h] = __builtin_amdgcn_mfma_f32_16x16x32_bf16(
                    af, cache[h], acc[h], 0, 0, 0);
        }
    }

    // ---- cross-wave reduction (LDS as 2 x 4096 f32, swizzled f32x4) ----
    __syncthreads();
    float* red = (float*)lds;
    const int jb = RSWZ(16 * nn + 4 * q);        // swizzled quad base in h-block

    if (wv >= 2) {
        float* dst = red + (wv - 2) * 4096;
#pragma unroll
        for (int h = 0; h < 16; ++h)
            *(f32x4*)(dst + 256 * h + jb) = acc[h];
    }
    __syncthreads();
    if (wv < 2) {
        const float* src = red + wv * 4096;
#pragma unroll
        for (int h = 0; h < 16; ++h) {
            f32x4 v = *(const f32x4*)(src + 256 * h + jb);
            acc[h] += v;
        }
    }
    __syncthreads();
    if (wv < 2) {
        float* dst = red + wv * 4096;
#pragma unroll
        for (int h = 0; h < 16; ++h)
            *(f32x4*)(dst + 256 * h + jb) = acc[h];
    }
    __syncthreads();

    // ---- final sum + store to own slab (block-private) ----
    float* slabf = (float*)(slab + O_OFF);
#pragma unroll
    for (int j = 0; j < 4; ++j) {
        int t = 4 * tid + 1024 * j;              // logical t, 4-aligned
        int ph = (t & ~255) + RSWZ(t & 255);     // physical (swizzled) index
        f32x4 v0 = *(const f32x4*)(red + ph);
        f32x4 v1 = *(const f32x4*)(red + 4096 + ph);
        *(f32x4*)(slabf + t) = v0 + v1;
    }
}

// ---------------------------------------------------------------------------
__global__ __launch_bounds__(256)
void k2_out(const unsigned short* __restrict__ ws, float* __restrict__ out) {
    __shared__ float tile[32][33];
    const int blk = blockIdx.x;
    const int b  = blk & 31;                     // bid%8 == b%8 (XCD-local)
    const int t0 = (blk >> 5) << 5;
    const int a  = threadIdx.x >> 5;
    const int j  = threadIdx.x & 31;

#pragma unroll
    for (int ff = a; ff < 32; ff += 8)
        tile[ff][j] =
            ((const float*)(ws + (size_t)(b * 32 + ff) * SLAB_US + O_OFF))[t0 + j];
    __syncthreads();
#pragma unroll
    for (int jj = a; jj < 32; jj += 8)
        out[b * (T_LEN * F_CH) + (t0 + jj) * F_CH + j] = tile[j][jj];
}

// ---------------------------------------------------------------------------
extern "C" void kernel_launch(void* const* d_in, const int* in_sizes, int n_in,
                              void* d_out, int out_size, void* d_ws, size_t ws_size,
                              hipStream_t stream) {
    const float* X = (const float*)d_in[0];
    float* out = (float*)d_out;
    (void)in_sizes; (void)n_in; (void)out_size; (void)ws_size;
    unsigned short* ws = (unsigned short*)d_ws;

    k0_stage<<<dim3(1024), dim3(256), 0, stream>>>(X, ws);
    corr1d_mfma_kernel<<<dim3(1024), dim3(256), 0, stream>>>(ws);
    k2_out<<<dim3(4096), dim3(256), 0, stream>>>(ws, out);
}

// Round 11
// 43.882 us; speedup vs baseline: 1.1696x; 1.0741x over previous
//
#include <hip/hip_runtime.h>

// ---------------------------------------------------------------------------
// Depthwise 1-D full correlation, per (batch, filter):
//   out[t] = sum_s y[s] * w[2047 + s - t],   t, s in [0, 4096)
// K0: transpose/convert X[b][s][c] (f32) -> bf16 slabs ws[(b,f)] = [y|w]
// K1: block-Toeplitz bf16 MFMA (16x16x32), fp32 accumulate; one block per
//     (b,f); WB (+1-shifted w) built during staging from registers; 2-deep
//     static-indexed A prefetch; swizzled f32x4 reduction; result f32
//     overwrites own slab (block-private).
// K2: 32x32 transpose slabs -> out[b][t][f]; f32x4 on both global sides;
//     one writer per 128-B output line.
// All three kernels decode b = bid&31 so bid%8 == b%8: slab pipeline stays
// XCD-local in L2.
// ---------------------------------------------------------------------------

#define T_LEN 4096
#define F_CH  32
#define SLAB_US 8192              // y[4096] | w[4096]  (bf16)

// K1 LDS layout (ushort units)
#define WAo    8448               // WA[16+i] = w[i]
#define WBo    12592              // WB[15+i] = w[i]  (built during staging)
#define LDS_US 17120              // 34240 B (pad covers tail prefetch reads)

using short8 = __attribute__((ext_vector_type(8))) short;
using f32x4  = __attribute__((ext_vector_type(4))) float;
using uint4v = __attribute__((ext_vector_type(4))) unsigned int;

__device__ __forceinline__ unsigned short bf16b(float x) {
    unsigned int u = __float_as_uint(x);
    u += 0x7FFFu + ((u >> 16) & 1u);      // RNE
    return (unsigned short)(u >> 16);
}

// y-region swizzle: granule g -> g ^ ((g>>3)&7)  (bijective per 8-block)
#define YADDR(e) ((((e) >> 3) ^ (((e) >> 6) & 7)) << 3)
// reduction swizzle within a 256-dword h-block: j ^ ((nn&7)<<2), nn = j>>4
#define RSWZ(j)  ((j) ^ ((((j) >> 4) & 7) << 2))

// ---------------------------------------------------------------------------
__global__ __launch_bounds__(256)
void k0_stage(const float* __restrict__ X, unsigned short* __restrict__ ws) {
    __shared__ unsigned short tile[64 * 130];
    const int tid = threadIdx.x;
    const int b  = blockIdx.x & 31;              // bid%8 == b%8 (XCD-local)
    const int s0 = (blockIdx.x >> 5) << 7;       // 128-row tile

    const float* xb = X + ((size_t)b * T_LEN + s0) * 64;
#pragma unroll
    for (int i = 0; i < 8; ++i) {
        int d4 = 4 * (tid + 256 * i);            // dword idx, 4 per thread
        int row = d4 >> 6, c0 = d4 & 63;
        f32x4 xv = *(const f32x4*)(xb + (size_t)row * 64 + c0);
#pragma unroll
        for (int k = 0; k < 4; ++k)
            tile[(c0 + k) * 130 + row] = bf16b(xv[k]);
    }
    __syncthreads();

    // y & w slabs, dword stores (coalesced per wave)
#pragma unroll
    for (int i = 0; i < 16; ++i) {
        int dw = tid + 256 * i;                  // 0..4095
        int c = dw >> 6, j0 = (dw & 63) * 2;
        unsigned int two = (unsigned int)tile[c * 130 + j0]
                         | ((unsigned int)tile[c * 130 + j0 + 1] << 16);
        unsigned short* slab;
        int off;
        if (c < 32) { slab = ws + (size_t)(b * 32 + c) * SLAB_US; off = s0 + j0; }
        else { slab = ws + (size_t)(b * 32 + (c - 32)) * SLAB_US; off = 4096 + s0 + j0; }
        *(unsigned int*)(slab + off) = two;
    }
}

// ---------------------------------------------------------------------------
__global__ __launch_bounds__(256, 3)
void corr1d_mfma_kernel(unsigned short* __restrict__ ws) {
    __shared__ __align__(16) unsigned short lds[LDS_US];
    const int tid = threadIdx.x;
    const int b = blockIdx.x & 31;               // bid%8 == b%8 (XCD-local)
    const int f = blockIdx.x >> 5;
    unsigned short* slab = ws + (size_t)(b * 32 + f) * SLAB_US;

    // ---- zero pad regions ----
    f32x4 z4 = (f32x4)0.0f;
    *(f32x4*)(lds + 8 * tid) = z4;                            // y gran [0,256)
    *(f32x4*)(lds + 8 * (768 + tid)) = z4;                    // y gran [768,1024)
    if (tid < 32) *(f32x4*)(lds + 8 * (1024 + tid)) = z4;     // y gran [1024,1056)
    if (tid < 2)       *(f32x4*)(lds + WAo + 8 * tid) = z4;              // WA [0,16)
    else if (tid < 6)  *(f32x4*)(lds + WAo + 4112 + 8 * (tid - 2)) = z4; // WA [4112,4144)
    else if (tid == 6) {
        *(f32x4*)(lds + WBo) = z4;                                       // WB [0,8)
        for (int i = 8; i < 14; ++i) lds[WBo + i] = 0;        // WB[8..14)
    } else if (tid >= 8 && tid < 12)
        *(f32x4*)(lds + WBo + 4112 + 8 * (tid - 8)) = z4;                // WB [4112,4144)

    // ---- stage y, WA, WB (coalesced uint4; WB shifted in registers) ----
    const uint4v* sv = (const uint4v*)slab;
    unsigned int* wb32 = (unsigned int*)(lds + WBo);
#pragma unroll
    for (int r = 0; r < 2; ++r) {
        int c = tid + 256 * r;                   // 0..511
        uint4v vy = sv[c];
        int g = 256 + c;
        *(uint4v*)(lds + ((g ^ ((g >> 3) & 7)) << 3)) = vy;   // swizzled y
        uint4v vw = sv[512 + c];                 // w[8c .. 8c+7]
        *(uint4v*)(lds + WAo + 16 + 8 * c) = vw;
        // WB[15+i] = w[i]: 4 shifted dwords at wb32[7+4c+k]
        unsigned int wm1 = (c == 0) ? 0u
                         : (unsigned int)slab[4096 + 8 * c - 1];
        unsigned int v0 = vw[0], v1 = vw[1], v2 = vw[2], v3 = vw[3];
        wb32[7 + 4 * c + 0] = (wm1 & 0xFFFFu) | (v0 << 16);
        wb32[7 + 4 * c + 1] = (v0 >> 16) | (v1 << 16);
        wb32[7 + 4 * c + 2] = (v1 >> 16) | (v2 << 16);
        wb32[7 + 4 * c + 3] = (v2 >> 16) | (v3 << 16);
        if (c == 511) wb32[2055] = (v3 >> 16);   // (w[4095], 0)
    }
    __syncthreads();

    // ---- compute (verified core; 2-deep static A prefetch) ----
    const int lane = tid & 63;
    const int wv   = tid >> 6;
    const int nn   = lane & 15;
    const int q    = lane >> 4;
    const int ko   = q << 3;

    f32x4 acc[16];
#pragma unroll
    for (int h = 0; h < 16; ++h) acc[h] = (f32x4)0.0f;

    short8 cache[16];

    const int tiOdd = nn & 1;
    const unsigned short* wbase = tiOdd ? &lds[WAo] : &lds[WBo];
    const int aoff0 = (tiOdd ? 15 : 14) + ko - nn;           // even, >= 0
    const unsigned short* ybase = &lds[0];
    const int yoff0 = 16 * nn + ko;

    for (int pp = 0; pp < 2; ++pp) {
        const int p = wv * 2 + pp;                           // pass 0..7
        const int yoff = yoff0 + 32 * p;
        const unsigned int* abase =
            (const unsigned int*)(wbase + (aoff0 + 32 * p));

#pragma unroll
        for (int s = 0; s < 16; ++s)
            cache[s] = *(const short8*)(ybase + YADDR(yoff + 256 * s));

        uint4v aPre[2];
#pragma unroll
        for (int s = 0; s < 2; ++s) {
            const unsigned int* ap = abase + 128 * s;
            aPre[s][0] = ap[0]; aPre[s][1] = ap[1];
            aPre[s][2] = ap[2]; aPre[s][3] = ap[3];
        }

#pragma unroll
        for (int M = 0; M < 16; ++M) {
            short8 af = __builtin_bit_cast(short8, aPre[M & 1]);
            if (M <= 14) {                       // prefetch A(M+2), static slot
                const unsigned int* ap = abase + 128 * (M + 2);
                aPre[M & 1][0] = ap[0]; aPre[M & 1][1] = ap[1];
                aPre[M & 1][2] = ap[2]; aPre[M & 1][3] = ap[3];
            }
            short8 bPre = *(const short8*)(ybase + YADDR(yoff + 256 * (M + 16)));
            __builtin_amdgcn_s_setprio(1);
#pragma unroll
            for (int h = 0; h < 16; ++h)
                acc[h] = __builtin_amdgcn_mfma_f32_16x16x32_bf16(
                    af, cache[(h + M) & 15], acc[h], 0, 0, 0);
            __builtin_amdgcn_s_setprio(0);
            cache[M] = bPre;
        }

        if (p == 0) {                            // extra M=16 (A(16) in slot 0)
            short8 af = __builtin_bit_cast(short8, aPre[0]);
            __builtin_amdgcn_s_setprio(1);
#pragma unroll
            for (int h = 0; h < 16; ++h)
                acc[h] = __builtin_amdgcn_mfma_f32_16x16x32_bf16(
                    af, cache[h], acc[h], 0, 0, 0);
            __builtin_amdgcn_s_setprio(0);
        }
    }

    // ---- cross-wave reduction (LDS as 2 x 4096 f32, swizzled f32x4) ----
    __syncthreads();
    float* red = (float*)lds;
    const int jb = RSWZ(16 * nn + 4 * q);        // swizzled quad base in h-block

    if (wv >= 2) {
        float* dst = red + (wv - 2) * 4096;
#pragma unroll
        for (int h = 0; h < 16; ++h)
            *(f32x4*)(dst + 256 * h + jb) = acc[h];
    }
    __syncthreads();
    if (wv < 2) {
        const float* src = red + wv * 4096;
#pragma unroll
        for (int h = 0; h < 16; ++h) {
            f32x4 v = *(const f32x4*)(src + 256 * h + jb);
            acc[h] += v;
        }
    }
    __syncthreads();
    if (wv < 2) {
        float* dst = red + wv * 4096;
#pragma unroll
        for (int h = 0; h < 16; ++h)
            *(f32x4*)(dst + 256 * h + jb) = acc[h];
    }
    __syncthreads();

    // ---- final sum + store to own slab (block-private) ----
    float* slabf = (float*)slab;
#pragma unroll
    for (int j = 0; j < 4; ++j) {
        int t = 4 * tid + 1024 * j;              // logical t, 4-aligned
        int ph = (t & ~255) + RSWZ(t & 255);     // physical (swizzled) index
        f32x4 v0 = *(const f32x4*)(red + ph);
        f32x4 v1 = *(const f32x4*)(red + 4096 + ph);
        *(f32x4*)(slabf + t) = v0 + v1;
    }
}

// ---------------------------------------------------------------------------
// K2: slab(b,f)[t] f32 -> out[b][t][f]; f32x4 global reads AND writes.
__global__ __launch_bounds__(256)
void k2_out(const unsigned short* __restrict__ ws, float* __restrict__ out) {
    __shared__ float tile[32][33];
    const int blk = blockIdx.x;
    const int b  = blk & 31;                     // bid%8 == b%8 (XCD-local)
    const int t0 = (blk >> 5) << 5;
    const int tid = threadIdx.x;

    // load: thread (f = tid>>3, k = tid&7) reads slab_f[t0+4k .. +3]
    {
        int f = tid >> 3, k = tid & 7;
        f32x4 v = *(const f32x4*)(
            (const float*)(ws + (size_t)(b * 32 + f) * SLAB_US) + t0 + 4 * k);
        tile[f][4 * k + 0] = v[0];
        tile[f][4 * k + 1] = v[1];
        tile[f][4 * k + 2] = v[2];
        tile[f][4 * k + 3] = v[3];
    }
    __syncthreads();
    // store: thread (tl = tid>>3, g = tid&7) writes out[b][t0+tl][4g .. +3]
    {
        int tl = tid >> 3, g = tid & 7;
        f32x4 v;
        v[0] = tile[4 * g + 0][tl];
        v[1] = tile[4 * g + 1][tl];
        v[2] = tile[4 * g + 2][tl];
        v[3] = tile[4 * g + 3][tl];
        *(f32x4*)(out + (size_t)b * (T_LEN * F_CH) + (t0 + tl) * F_CH + 4 * g) = v;
    }
}

// ---------------------------------------------------------------------------
extern "C" void kernel_launch(void* const* d_in, const int* in_sizes, int n_in,
                              void* d_out, int out_size, void* d_ws, size_t ws_size,
                              hipStream_t stream) {
    const float* X = (const float*)d_in[0];
    float* out = (float*)d_out;
    (void)in_sizes; (void)n_in; (void)out_size; (void)ws_size;
    unsigned short* ws = (unsigned short*)d_ws;

    k0_stage<<<dim3(1024), dim3(256), 0, stream>>>(X, ws);
    corr1d_mfma_kernel<<<dim3(1024), dim3(256), 0, stream>>>(ws);
    k2_out<<<dim3(4096), dim3(256), 0, stream>>>(ws, out);
}